// Round 1
// 679.623 us; speedup vs baseline: 1.0023x; 1.0023x over previous
//
#include <hip/hip_runtime.h>
#include <math.h>

typedef float f32x4 __attribute__((ext_vector_type(4)));
typedef short bf16x8 __attribute__((ext_vector_type(8)));
typedef unsigned int u32;
typedef unsigned long long u64;

constexpr int N_NODES = 32768;
constexpr int LEN     = 3000;
constexpr int HID     = 128;
constexpr int OUT3    = 64;
constexpr int E_TOT   = 32768*16;
constexpr int PG      = 64;
constexpr int EPG     = 1024;
constexpr int NG      = 512;
constexpr int NCHUNK  = 25;          // 25 chunks x 6 r-positions (last has 2 valid)
constexpr int XS_S    = 260;         // ring stride (shorts); 130 dw -> mild conflicts, 8B aligned rows
constexpr int CBS     = 196;         // cbuf stride (shorts); 392 B, 8B aligned rows

// ---- bf16 helpers ----
__device__ __forceinline__ short bf1(float a) {          // RNE (cold pack kernels)
    unsigned u = __float_as_uint(a);
    return (short)((u + 0x7fff + ((u >> 16) & 1)) >> 16);
}
__device__ __forceinline__ u32 pk2(float lo, float hi) { // round-half-up (hot path, 3 VALU)
    u32 ua = __float_as_uint(lo) + 0x8000u;
    u32 ub = __float_as_uint(hi) + 0x8000u;
    return (ua >> 16) | (ub & 0xffff0000u);
}

// Non-draining workgroup barrier: completes this wave's LDS ops (lgkmcnt) but
// leaves global prefetches in flight across the barrier (avoids the
// compiler-emitted s_waitcnt vmcnt(0) that __syncthreads() forces).
__device__ __forceinline__ void bar_lds() {
    asm volatile("s_waitcnt lgkmcnt(0)" ::: "memory");
    __builtin_amdgcn_s_barrier();
}

// ================= pre-pack conv weights into A-fragment order ==============
// wPf[(Mt*4+ks)*64 + lane][8]: A[c][k], c = Mt*16+(lane&15), k = ks*32+(lane>>4)*8+j
__global__ void pack_w(const float* __restrict__ cw, short* __restrict__ wPf) {
    int tid = blockIdx.x * 256 + threadIdx.x;
    if (tid >= 512) return;
    int lane = tid & 63, i = tid >> 6;
    int Mt = i >> 2, ks = i & 3;
    int c  = Mt * 16 + (lane & 15);
    int kb = ks * 32 + (lane >> 4) * 8;
    bf16x8 v;
    #pragma unroll
    for (int j = 0; j < 8; j++) {
        int k = kb + j;
        v[j] = (k < 100) ? bf1(cw[c * 100 + k]) : (short)0;
    }
    *(bf16x8*)(wPf + tid * 8) = v;
}

// ============== pre-pack W1 into B-fragment order (per chunk) ===============
__global__ void pack_w1(const float* __restrict__ W1, short* __restrict__ w1f) {
    int tid = blockIdx.x * 256 + threadIdx.x;     // < 76800
    if (tid >= 76800) return;
    int lane  = tid & 63;
    int rest  = tid >> 6;                          // < 1200
    int ks    = rest % 6;
    int rest2 = rest / 6;                          // < 200
    int Nt    = rest2 & 7, chunk = rest2 >> 3;
    int r  = chunk * 6 + ks;
    int n  = Nt * 16 + (lane & 15);
    int cb = (lane >> 4) * 8;
    bf16x8 v;
    #pragma unroll
    for (int j = 0; j < 8; j++) {
        int c = cb + j;
        v[j] = (r < 146) ? bf1(W1[(c * 146 + r) * 128 + n]) : (short)0;
    }
    *(bf16x8*)(w1f + tid * 8) = v;
}

// ========== fused conv1d+relu+GEMM1, bf16 MFMA, wave-private x ring =========
// 64 nodes/WG, 16 nodes/wave. rr-major conv (B n-index = node = lane&15):
// xs is wave-private -> no staging barriers; x software-pipelined via VGPRs.
// Only cbuf needs 2 barriers/chunk. LDS 58.4KB -> 2 WG/CU.
// Barriers are raw s_barrier + lgkmcnt(0) so the x/w1f prefetches issued at
// the loop top stay in flight across barrier #1 (no vmcnt drain).
__global__ __launch_bounds__(256, 2) void conv_gemm1_mfma(
    const float* __restrict__ x, const short* __restrict__ wPf,
    const float* __restrict__ cbv, const short* __restrict__ w1f,
    float* __restrict__ z)
{
    __shared__ short xs[64 * XS_S];    // ring: 256 logical elems/node
    __shared__ short cbuf[64 * CBS];   // [node][kl = rr*32 + c]

    const int t     = threadIdx.x;
    const int lane  = t & 63;
    const int wv    = t >> 6;
    const int l15   = lane & 15;
    const int q     = lane >> 4;
    const int n0    = blockIdx.x * 64;
    const int j4    = lane & 3;
    const int nodeS = wv * 16 + (lane >> 2);   // staging node (4 lanes/node)
    const int nodeC = wv * 16 + l15;           // conv node

    // conv A-frags (weights) + per-lane conv bias rows
    bf16x8 wA[8];
    #pragma unroll
    for (int i = 0; i < 8; i++)
        wA[i] = *(const bf16x8*)(wPf + (i * 64 + lane) * 8);
    float cbr[8];                      // c = (i>>2)*16 + q*4 + (i&3)
    #pragma unroll
    for (int i = 0; i < 8; i++)
        cbr[i] = cbv[(i >> 2) * 16 + q * 4 + (i & 3)];

    f32x4 acc[4][2];                   // [node mt][gemm Nt-pair]
    #pragma unroll
    for (int a = 0; a < 4; a++) { acc[a][0] = (f32x4)0.0f; acc[a][1] = (f32x4)0.0f; }

    const int NtG0 = wv * 2;           // this wave's 2 gemm N-tiles
    const float* xpS = x + (size_t)(n0 + nodeS) * LEN;
    short* xrow = xs + nodeS * XS_S;

    // ---- initial stage: elements [0,208) for this wave's nodes (wave-private) ----
    {
        float4 v[13];
        #pragma unroll
        for (int it = 0; it < 13; it++)
            v[it] = *(const float4*)(xpS + (j4 + 4 * it) * 4);
        #pragma unroll
        for (int it = 0; it < 13; it++) {
            int e = (j4 + 4 * it) * 4;
            *(uint2*)&xrow[e] = make_uint2(pk2(v[it].x, v[it].y), pk2(v[it].z, v[it].w));
        }
    }

    #pragma unroll 1
    for (int c = 0; c < NCHUNK; c++) {
        const int r0 = c * 6;
        const int rcount = (146 - r0 < 6) ? (146 - r0) : 6;

        // prefetch next chunk's new x range [120c+200, 120c+320) into VGPRs
        float4 xn[8];
        if (c < NCHUNK - 1) {
            const int ebase = 120 * c + 200;
            #pragma unroll
            for (int it = 0; it < 8; it++) {
                int e  = ebase + (j4 + 4 * it) * 4;
                int ge = e > 2996 ? 2996 : e;          // clamp; garbage lands in masked/overwritten slots
                xn[it] = *(const float4*)(xpS + ge);
            }
        }
        // prefetch this chunk's W1 B-frags (global; consumed after barrier #2)
        bf16x8 wB[12];                 // [nt2*6 + ks]
        #pragma unroll
        for (int u = 0; u < 12; u++)
            wB[u] = *(const bf16x8*)(w1f + ((c * 48 + NtG0 * 6 + u) * 64 + lane) * 8);

        bar_lds();                     // barrier #1: prev GEMM done reading cbuf
                                       // (x/wB prefetches stay in flight)

        // ---- conv via MFMA: D[c'][node], node = wave's 16 nodes ----
        const short* xr = xs + nodeC * XS_S;
        #pragma unroll
        for (int rr = 0; rr < 6; rr++) {
            const int eb = 20 * (r0 + rr) + 8 * q;
            f32x4 ca0 = (f32x4)0.0f, ca1 = (f32x4)0.0f;
            #pragma unroll
            for (int ks = 0; ks < 4; ks++) {
                int e0 = eb + 32 * ks;
                bf16x8 bx;
                *(u64*)&bx       = *(const u64*)&xr[e0 & 255];
                *((u64*)&bx + 1) = *(const u64*)&xr[(e0 + 4) & 255];
                ca0 = __builtin_amdgcn_mfma_f32_16x16x32_bf16(wA[ks],     bx, ca0, 0, 0, 0);
                ca1 = __builtin_amdgcn_mfma_f32_16x16x32_bf16(wA[4 + ks], bx, ca1, 0, 0, 0);
            }
            short* cw_ = cbuf + nodeC * CBS + rr * 32 + q * 4;
            if (rr < rcount) {
                u32 p0 = pk2(fmaxf(ca0[0] + cbr[0], 0.f), fmaxf(ca0[1] + cbr[1], 0.f));
                u32 p1 = pk2(fmaxf(ca0[2] + cbr[2], 0.f), fmaxf(ca0[3] + cbr[3], 0.f));
                *(uint2*)cw_ = make_uint2(p0, p1);
                p0 = pk2(fmaxf(ca1[0] + cbr[4], 0.f), fmaxf(ca1[1] + cbr[5], 0.f));
                p1 = pk2(fmaxf(ca1[2] + cbr[6], 0.f), fmaxf(ca1[3] + cbr[7], 0.f));
                *(uint2*)(cw_ + 16) = make_uint2(p0, p1);
            } else {
                *(uint2*)cw_        = make_uint2(0u, 0u);
                *(uint2*)(cw_ + 16) = make_uint2(0u, 0u);
            }
        }

        // ---- write prefetched x into ring (wave-private; after own conv reads) ----
        if (c < NCHUNK - 1) {
            const int ebase = 120 * c + 200;
            #pragma unroll
            for (int it = 0; it < 8; it++) {
                int e = ebase + (j4 + 4 * it) * 4;
                *(uint2*)&xrow[e & 255] = make_uint2(pk2(xn[it].x, xn[it].y), pk2(xn[it].z, xn[it].w));
            }
        }

        bar_lds();                     // barrier #2: cbuf ready (wB vmcnt-waited at use)

        // ---- GEMM1: acc[node][f] += cbuf * W1frags ----
        #pragma unroll
        for (int ks = 0; ks < 6; ks++) {
            bf16x8 af[4];
            #pragma unroll
            for (int mt = 0; mt < 4; mt++) {
                const short* ap = cbuf + (mt * 16 + l15) * CBS + ks * 32 + q * 8;
                *(u64*)&af[mt]       = *(const u64*)ap;
                *((u64*)&af[mt] + 1) = *(const u64*)(ap + 4);
            }
            #pragma unroll
            for (int mt = 0; mt < 4; mt++) {
                acc[mt][0] = __builtin_amdgcn_mfma_f32_16x16x32_bf16(af[mt], wB[ks],     acc[mt][0], 0, 0, 0);
                acc[mt][1] = __builtin_amdgcn_mfma_f32_16x16x32_bf16(af[mt], wB[6 + ks], acc[mt][1], 0, 0, 0);
            }
        }
    }

    // epilogue: z[node][f] fp32
    #pragma unroll
    for (int mt = 0; mt < 4; mt++)
        #pragma unroll
        for (int nt2 = 0; nt2 < 2; nt2++)
            #pragma unroll
            for (int reg = 0; reg < 4; reg++) {
                int node = n0 + mt * 16 + q * 4 + reg;
                int f    = (NtG0 + nt2) * 16 + l15;
                z[(size_t)node * HID + f] = acc[mt][nt2][reg];
            }
}

// ====== per-graph fused: deg + dense-A + 3x(GCN agg+BN+ReLU) + GEMMs + pool+FC
__global__ __launch_bounds__(256) void graph_block(
    const float* __restrict__ z, const int* __restrict__ ei,
    const float* __restrict__ ew,
    const float* __restrict__ b1, const float* __restrict__ g1, const float* __restrict__ be1,
    const float* __restrict__ m1, const float* __restrict__ v1,
    const float* __restrict__ W2,
    const float* __restrict__ b2, const float* __restrict__ g2, const float* __restrict__ be2,
    const float* __restrict__ m2, const float* __restrict__ v2,
    const float* __restrict__ W3,
    const float* __restrict__ b3, const float* __restrict__ g3, const float* __restrict__ be3,
    const float* __restrict__ m3, const float* __restrict__ v3,
    const float* __restrict__ fcw, const float* __restrict__ fcb,
    float* __restrict__ out)
{
    __shared__ float At[64 * 68];     // [src][dst], padded
    __shared__ float buf[8704];       // union: zb[64][128] / hT[128][68] / zb64[64][64]
    __shared__ float dl[64];
    __shared__ float ps4[256];
    __shared__ float pooled[64];

    const int t  = threadIdx.x;
    const int g  = blockIdx.x;
    const int nb = g * PG;

    for (int i = t; i < 64 * 68; i += 256) At[i] = 0.f;
    if (t < 64) dl[t] = 0.f;
    __syncthreads();
    for (int i = t; i < EPG; i += 256) {
        int e = g * EPG + i;
        atomicAdd(&dl[ei[E_TOT + e] - nb], ew[e]);
    }
    __syncthreads();
    if (t < 64) dl[t] = rsqrtf(dl[t] + 1.0f);
    __syncthreads();
    for (int i = t; i < EPG; i += 256) {
        int e = g * EPG + i;
        int s = ei[e] - nb, d = ei[E_TOT + e] - nb;
        atomicAdd(&At[s * 68 + d], dl[s] * ew[e] * dl[d]);
    }
    if (t < 64) atomicAdd(&At[t * 68 + t], dl[t] * dl[t]);   // self-loop
    for (int i = t; i < 64 * HID; i += 256) buf[i] = z[(size_t)nb * HID + i];
    __syncthreads();

    const int f   = t & 127;
    const int ng  = t >> 7;
    const int n0  = ng * 32;
    const int f3  = t & 63;
    const int ng3 = t >> 6;
    const int n03 = ng3 * 16;

    float hreg[32];

#define LAYER128(BB, GG, BE, MM, VV)                                          \
    {                                                                         \
        float sc = GG[f] * rsqrtf(VV[f] + 1e-5f);                             \
        float mu = MM[f], bt = BE[f], bb = BB[f];                             \
        float a[32];                                                          \
        _Pragma("unroll")                                                     \
        for (int i = 0; i < 32; i++) a[i] = 0.f;                              \
        _Pragma("unroll 2")                                                   \
        for (int s = 0; s < 64; s++) {                                        \
            float zv = buf[s * 128 + f];                                      \
            _Pragma("unroll")                                                 \
            for (int qq = 0; qq < 8; qq++) {                                  \
                float4 a4 = *(const float4*)&At[s * 68 + n0 + qq * 4];        \
                a[qq*4+0] += a4.x * zv; a[qq*4+1] += a4.y * zv;               \
                a[qq*4+2] += a4.z * zv; a[qq*4+3] += a4.w * zv;               \
            }                                                                 \
        }                                                                     \
        _Pragma("unroll")                                                     \
        for (int i = 0; i < 32; i++)                                          \
            hreg[i] = fmaxf((a[i] + bb - mu) * sc + bt, 0.f);                 \
    }                                                                         \
    __syncthreads();                                                          \
    _Pragma("unroll")                                                         \
    for (int qq = 0; qq < 8; qq++)                                            \
        *(float4*)&buf[f * 68 + n0 + qq * 4] =                                \
            make_float4(hreg[qq*4], hreg[qq*4+1], hreg[qq*4+2], hreg[qq*4+3]);\
    __syncthreads();

#define GEMM128(WPTR)                                                         \
    {                                                                         \
        float a[32];                                                          \
        _Pragma("unroll")                                                     \
        for (int i = 0; i < 32; i++) a[i] = 0.f;                              \
        _Pragma("unroll 2")                                                   \
        for (int k = 0; k < 128; k++) {                                       \
            float wvv = WPTR[k * 128 + f];                                    \
            _Pragma("unroll")                                                 \
            for (int qq = 0; qq < 8; qq++) {                                  \
                float4 h4 = *(const float4*)&buf[k * 68 + n0 + qq * 4];       \
                a[qq*4+0] += h4.x * wvv; a[qq*4+1] += h4.y * wvv;             \
                a[qq*4+2] += h4.z * wvv; a[qq*4+3] += h4.w * wvv;             \
            }                                                                 \
        }                                                                     \
        __syncthreads();                                                      \
        _Pragma("unroll")                                                     \
        for (int i = 0; i < 32; i++) buf[(n0 + i) * 128 + f] = a[i];          \
        __syncthreads();                                                      \
    }

    LAYER128(b1, g1, be1, m1, v1)      // layer 1 -> hT in buf
    GEMM128(W2)                        // z2 -> zb in buf
    LAYER128(b2, g2, be2, m2, v2)      // layer 2 -> hT in buf

    // GEMM3: z3[n][f3] (OUT3=64)
    {
        float a[16];
        #pragma unroll
        for (int i = 0; i < 16; i++) a[i] = 0.f;
        #pragma unroll 2
        for (int k = 0; k < 128; k++) {
            float wvv = W3[k * 64 + f3];
            #pragma unroll
            for (int qq = 0; qq < 4; qq++) {
                float4 h4 = *(const float4*)&buf[k * 68 + n03 + qq * 4];
                a[qq*4+0] += h4.x * wvv; a[qq*4+1] += h4.y * wvv;
                a[qq*4+2] += h4.z * wvv; a[qq*4+3] += h4.w * wvv;
            }
        }
        __syncthreads();
        #pragma unroll
        for (int i = 0; i < 16; i++) buf[(n03 + i) * 64 + f3] = a[i];
        __syncthreads();
    }

    // layer 3 agg + BN + ReLU + pool partial
    {
        float sc = g3[f3] * rsqrtf(v3[f3] + 1e-5f);
        float mu = m3[f3], bt = be3[f3], bb = b3[f3];
        float a[16];
        #pragma unroll
        for (int i = 0; i < 16; i++) a[i] = 0.f;
        #pragma unroll 2
        for (int s = 0; s < 64; s++) {
            float zv = buf[s * 64 + f3];
            #pragma unroll
            for (int qq = 0; qq < 4; qq++) {
                float4 a4 = *(const float4*)&At[s * 68 + n03 + qq * 4];
                a[qq*4+0] += a4.x * zv; a[qq*4+1] += a4.y * zv;
                a[qq*4+2] += a4.z * zv; a[qq*4+3] += a4.w * zv;
            }
        }
        float psum = 0.f;
        #pragma unroll
        for (int i = 0; i < 16; i++)
            psum += fmaxf((a[i] + bb - mu) * sc + bt, 0.f);
        ps4[ng3 * 64 + f3] = psum;
    }
    __syncthreads();
    if (t < 64) pooled[t] = (ps4[t] + ps4[64 + t] + ps4[128 + t] + ps4[192 + t]) * (1.f / 64.f);
    __syncthreads();
    if (t == 0) {
        float l0 = fcb[0], l1 = fcb[1];
        for (int ff = 0; ff < 64; ff++) { l0 += pooled[ff] * fcw[ff * 2]; l1 += pooled[ff] * fcw[ff * 2 + 1]; }
        float mx  = fmaxf(l0, l1);
        float lse = mx + logf(expf(l0 - mx) + expf(l1 - mx));
        out[g * 2 + 0] = l0 - lse;
        out[g * 2 + 1] = l1 - lse;
    }
#undef LAYER128
#undef GEMM128
}

// ---------------------------------------------------------------- launch
extern "C" void kernel_launch(void* const* d_in, const int* in_sizes, int n_in,
                              void* d_out, int out_size, void* d_ws, size_t ws_size,
                              hipStream_t stream) {
    const float* x   = (const float*)d_in[0];
    const int*   ei  = (const int*)  d_in[1];
    const float* ew  = (const float*)d_in[2];
    const float* cw  = (const float*)d_in[4];
    const float* cb  = (const float*)d_in[5];
    const float* W1  = (const float*)d_in[6];
    const float* b1  = (const float*)d_in[7];
    const float* W2  = (const float*)d_in[8];
    const float* b2  = (const float*)d_in[9];
    const float* W3  = (const float*)d_in[10];
    const float* b3  = (const float*)d_in[11];
    const float* g1  = (const float*)d_in[12];
    const float* be1 = (const float*)d_in[13];
    const float* m1  = (const float*)d_in[14];
    const float* v1  = (const float*)d_in[15];
    const float* g2  = (const float*)d_in[16];
    const float* be2 = (const float*)d_in[17];
    const float* m2  = (const float*)d_in[18];
    const float* v2  = (const float*)d_in[19];
    const float* g3  = (const float*)d_in[20];
    const float* be3 = (const float*)d_in[21];
    const float* m3  = (const float*)d_in[22];
    const float* v3  = (const float*)d_in[23];
    const float* fcw = (const float*)d_in[24];
    const float* fcb = (const float*)d_in[25];
    float* out = (float*)d_out;

    float* z   = (float*)d_ws;                            // 16,777,216 B
    short* wPf = (short*)((char*)d_ws + 16777216);        // 8,192 B
    short* w1f = (short*)((char*)d_ws + 16785408);        // 1,228,800 B

    pack_w  <<<2,   256, 0, stream>>>(cw, wPf);
    pack_w1 <<<300, 256, 0, stream>>>(W1, w1f);
    conv_gemm1_mfma<<<NG, 256, 0, stream>>>(x, wPf, cb, w1f, z);
    graph_block<<<NG, 256, 0, stream>>>(z, ei, ew,
        b1, g1, be1, m1, v1, W2,
        b2, g2, be2, m2, v2, W3,
        b3, g3, be3, m3, v3, fcw, fcb, out);
}

// Round 2
// 671.456 us; speedup vs baseline: 1.0145x; 1.0122x over previous
//
#include <hip/hip_runtime.h>
#include <math.h>

typedef float f32x4 __attribute__((ext_vector_type(4)));
typedef short bf16x8 __attribute__((ext_vector_type(8)));
typedef unsigned int u32;
typedef unsigned long long u64;

constexpr int N_NODES = 32768;
constexpr int LEN     = 3000;
constexpr int HID     = 128;
constexpr int OUT3    = 64;
constexpr int E_TOT   = 32768*16;
constexpr int PG      = 64;
constexpr int EPG     = 1024;
constexpr int NG      = 512;
constexpr int NCHUNK  = 25;          // 25 chunks x 6 r-positions (last has 2 valid)
constexpr int XS_S    = 260;         // ring stride (shorts); 130 dw -> mild conflicts, 8B aligned rows
constexpr int CBS     = 196;         // cbuf stride (shorts); 392 B, 8B aligned rows

// ---- bf16 helpers ----
__device__ __forceinline__ short bf1(float a) {          // RNE (cold pack kernels)
    unsigned u = __float_as_uint(a);
    return (short)((u + 0x7fff + ((u >> 16) & 1)) >> 16);
}
__device__ __forceinline__ u32 pk2(float lo, float hi) { // round-half-up (hot path, 3 VALU)
    u32 ua = __float_as_uint(lo) + 0x8000u;
    u32 ub = __float_as_uint(hi) + 0x8000u;
    return (ua >> 16) | (ub & 0xffff0000u);
}

// Non-draining workgroup barrier: completes this wave's LDS ops (lgkmcnt) but
// leaves global prefetches in flight across the barrier.
__device__ __forceinline__ void bar_lds() {
    asm volatile("s_waitcnt lgkmcnt(0)" ::: "memory");
    __builtin_amdgcn_s_barrier();
}

// ================= pre-pack conv weights into A-fragment order ==============
__global__ void pack_w(const float* __restrict__ cw, short* __restrict__ wPf) {
    int tid = blockIdx.x * 256 + threadIdx.x;
    if (tid >= 512) return;
    int lane = tid & 63, i = tid >> 6;
    int Mt = i >> 2, ks = i & 3;
    int c  = Mt * 16 + (lane & 15);
    int kb = ks * 32 + (lane >> 4) * 8;
    bf16x8 v;
    #pragma unroll
    for (int j = 0; j < 8; j++) {
        int k = kb + j;
        v[j] = (k < 100) ? bf1(cw[c * 100 + k]) : (short)0;
    }
    *(bf16x8*)(wPf + tid * 8) = v;
}

// ============== pre-pack W1 into B-fragment order (per chunk) ===============
__global__ void pack_w1(const float* __restrict__ W1, short* __restrict__ w1f) {
    int tid = blockIdx.x * 256 + threadIdx.x;     // < 76800
    if (tid >= 76800) return;
    int lane  = tid & 63;
    int rest  = tid >> 6;                          // < 1200
    int ks    = rest % 6;
    int rest2 = rest / 6;                          // < 200
    int Nt    = rest2 & 7, chunk = rest2 >> 3;
    int r  = chunk * 6 + ks;
    int n  = Nt * 16 + (lane & 15);
    int cb = (lane >> 4) * 8;
    bf16x8 v;
    #pragma unroll
    for (int j = 0; j < 8; j++) {
        int c = cb + j;
        v[j] = (r < 146) ? bf1(W1[(c * 146 + r) * 128 + n]) : (short)0;
    }
    *(bf16x8*)(w1f + tid * 8) = v;
}

// ===== FUSED: conv1d+relu+GEMM1 (bf16 MFMA) -> per-graph GCN tail ==========
// Phase 1: conv+GEMM1 exactly as before; z stays in acc registers.
// Phase 2: graph block (deg + dense-A + 3x agg/BN/ReLU + GEMMs + pool + FC)
// on the SAME 64 nodes this block just produced. z never touches HBM.
// LDS is a union: phase1 xs+cbuf (58,368 B) / phase2 At+buf+misc (53,760 B).
__global__ __launch_bounds__(256, 2) void fused_all(
    const float* __restrict__ x, const short* __restrict__ wPf,
    const float* __restrict__ cbv, const short* __restrict__ w1f,
    const int* __restrict__ ei, const float* __restrict__ ew,
    const float* __restrict__ b1, const float* __restrict__ g1, const float* __restrict__ be1,
    const float* __restrict__ m1, const float* __restrict__ v1,
    const float* __restrict__ W2,
    const float* __restrict__ b2, const float* __restrict__ g2, const float* __restrict__ be2,
    const float* __restrict__ m2, const float* __restrict__ v2,
    const float* __restrict__ W3,
    const float* __restrict__ b3, const float* __restrict__ g3, const float* __restrict__ be3,
    const float* __restrict__ m3, const float* __restrict__ v3,
    const float* __restrict__ fcw, const float* __restrict__ fcb,
    float* __restrict__ out)
{
    __shared__ __align__(16) char smraw[58368];
    // phase-1 views
    short* xs   = (short*)smraw;                    // [64][XS_S]   33,280 B
    short* cbuf = (short*)(smraw + 64 * XS_S * 2);  // [64][CBS]    25,088 B
    // phase-2 views (overlay)
    float* At     = (float*)smraw;                  // [64][68]     17,408 B
    float* buf    = (float*)(smraw + 17408);        // [8704]       34,816 B
    float* dl     = (float*)(smraw + 52224);        // [64]
    float* ps4    = (float*)(smraw + 52480);        // [256]
    float* pooled = (float*)(smraw + 53504);        // [64]

    const int t     = threadIdx.x;
    const int lane  = t & 63;
    const int wv    = t >> 6;
    const int l15   = lane & 15;
    const int q     = lane >> 4;
    const int g     = blockIdx.x;
    const int nbase = g * 64;
    const int j4    = lane & 3;
    const int nodeS = wv * 16 + (lane >> 2);   // staging node (4 lanes/node)
    const int nodeC = wv * 16 + l15;           // conv node

    // conv A-frags (weights) + per-lane conv bias rows
    bf16x8 wA[8];
    #pragma unroll
    for (int i = 0; i < 8; i++)
        wA[i] = *(const bf16x8*)(wPf + (i * 64 + lane) * 8);
    float cbr[8];                      // c = (i>>2)*16 + q*4 + (i&3)
    #pragma unroll
    for (int i = 0; i < 8; i++)
        cbr[i] = cbv[(i >> 2) * 16 + q * 4 + (i & 3)];

    f32x4 acc[4][2];                   // [node mt][gemm Nt-pair]
    #pragma unroll
    for (int a = 0; a < 4; a++) { acc[a][0] = (f32x4)0.0f; acc[a][1] = (f32x4)0.0f; }

    const int NtG0 = wv * 2;           // this wave's 2 gemm N-tiles
    const float* xpS = x + (size_t)(nbase + nodeS) * LEN;
    short* xrow = xs + nodeS * XS_S;

    // ---- initial stage: elements [0,208) for this wave's nodes ----
    {
        float4 v[13];
        #pragma unroll
        for (int it = 0; it < 13; it++)
            v[it] = *(const float4*)(xpS + (j4 + 4 * it) * 4);
        #pragma unroll
        for (int it = 0; it < 13; it++) {
            int e = (j4 + 4 * it) * 4;
            *(uint2*)&xrow[e] = make_uint2(pk2(v[it].x, v[it].y), pk2(v[it].z, v[it].w));
        }
    }

    #pragma unroll 1
    for (int c = 0; c < NCHUNK; c++) {
        const int r0 = c * 6;
        const int rcount = (146 - r0 < 6) ? (146 - r0) : 6;

        // prefetch next chunk's new x range [120c+200, 120c+320) into VGPRs
        float4 xn[8];
        if (c < NCHUNK - 1) {
            const int ebase = 120 * c + 200;
            #pragma unroll
            for (int it = 0; it < 8; it++) {
                int e  = ebase + (j4 + 4 * it) * 4;
                int ge = e > 2996 ? 2996 : e;          // clamp
                xn[it] = *(const float4*)(xpS + ge);
            }
        }
        // prefetch this chunk's W1 B-frags (global; consumed after barrier #2)
        bf16x8 wB[12];                 // [nt2*6 + ks]
        #pragma unroll
        for (int u = 0; u < 12; u++)
            wB[u] = *(const bf16x8*)(w1f + ((c * 48 + NtG0 * 6 + u) * 64 + lane) * 8);

        bar_lds();                     // barrier #1: prev GEMM done reading cbuf

        // ---- conv via MFMA: D[c'][node] ----
        const short* xr = xs + nodeC * XS_S;
        #pragma unroll
        for (int rr = 0; rr < 6; rr++) {
            const int eb = 20 * (r0 + rr) + 8 * q;
            f32x4 ca0 = (f32x4)0.0f, ca1 = (f32x4)0.0f;
            #pragma unroll
            for (int ks = 0; ks < 4; ks++) {
                int e0 = eb + 32 * ks;
                bf16x8 bx;
                *(u64*)&bx       = *(const u64*)&xr[e0 & 255];
                *((u64*)&bx + 1) = *(const u64*)&xr[(e0 + 4) & 255];
                ca0 = __builtin_amdgcn_mfma_f32_16x16x32_bf16(wA[ks],     bx, ca0, 0, 0, 0);
                ca1 = __builtin_amdgcn_mfma_f32_16x16x32_bf16(wA[4 + ks], bx, ca1, 0, 0, 0);
            }
            short* cw_ = cbuf + nodeC * CBS + rr * 32 + q * 4;
            if (rr < rcount) {
                u32 p0 = pk2(fmaxf(ca0[0] + cbr[0], 0.f), fmaxf(ca0[1] + cbr[1], 0.f));
                u32 p1 = pk2(fmaxf(ca0[2] + cbr[2], 0.f), fmaxf(ca0[3] + cbr[3], 0.f));
                *(uint2*)cw_ = make_uint2(p0, p1);
                p0 = pk2(fmaxf(ca1[0] + cbr[4], 0.f), fmaxf(ca1[1] + cbr[5], 0.f));
                p1 = pk2(fmaxf(ca1[2] + cbr[6], 0.f), fmaxf(ca1[3] + cbr[7], 0.f));
                *(uint2*)(cw_ + 16) = make_uint2(p0, p1);
            } else {
                *(uint2*)cw_        = make_uint2(0u, 0u);
                *(uint2*)(cw_ + 16) = make_uint2(0u, 0u);
            }
        }

        // ---- write prefetched x into ring ----
        if (c < NCHUNK - 1) {
            const int ebase = 120 * c + 200;
            #pragma unroll
            for (int it = 0; it < 8; it++) {
                int e = ebase + (j4 + 4 * it) * 4;
                *(uint2*)&xrow[e & 255] = make_uint2(pk2(xn[it].x, xn[it].y), pk2(xn[it].z, xn[it].w));
            }
        }

        bar_lds();                     // barrier #2: cbuf ready

        // ---- GEMM1: acc[node][f] += cbuf * W1frags ----
        #pragma unroll
        for (int ks = 0; ks < 6; ks++) {
            bf16x8 af[4];
            #pragma unroll
            for (int mt = 0; mt < 4; mt++) {
                const short* ap = cbuf + (mt * 16 + l15) * CBS + ks * 32 + q * 8;
                *(u64*)&af[mt]       = *(const u64*)ap;
                *((u64*)&af[mt] + 1) = *(const u64*)(ap + 4);
            }
            #pragma unroll
            for (int mt = 0; mt < 4; mt++) {
                acc[mt][0] = __builtin_amdgcn_mfma_f32_16x16x32_bf16(af[mt], wB[ks],     acc[mt][0], 0, 0, 0);
                acc[mt][1] = __builtin_amdgcn_mfma_f32_16x16x32_bf16(af[mt], wB[6 + ks], acc[mt][1], 0, 0, 0);
            }
        }
    }

    __syncthreads();                   // conv LDS dead; switch to graph layout

    // ================= phase 2: per-graph GCN tail =================
    const int nb = nbase;

    // zero At/dl; spill z tile from acc registers into buf[node][128]
    for (int i = t; i < 64 * 68; i += 256) At[i] = 0.f;
    if (t < 64) dl[t] = 0.f;
    #pragma unroll
    for (int mt = 0; mt < 4; mt++)
        #pragma unroll
        for (int nt2 = 0; nt2 < 2; nt2++)
            #pragma unroll
            for (int reg = 0; reg < 4; reg++) {
                int node = mt * 16 + q * 4 + reg;
                int f    = (NtG0 + nt2) * 16 + l15;
                buf[node * 128 + f] = acc[mt][nt2][reg];
            }
    __syncthreads();
    for (int i = t; i < EPG; i += 256) {
        int e = g * EPG + i;
        atomicAdd(&dl[ei[E_TOT + e] - nb], ew[e]);
    }
    __syncthreads();
    if (t < 64) dl[t] = rsqrtf(dl[t] + 1.0f);
    __syncthreads();
    for (int i = t; i < EPG; i += 256) {
        int e = g * EPG + i;
        int s = ei[e] - nb, d = ei[E_TOT + e] - nb;
        atomicAdd(&At[s * 68 + d], dl[s] * ew[e] * dl[d]);
    }
    if (t < 64) atomicAdd(&At[t * 68 + t], dl[t] * dl[t]);   // self-loop
    __syncthreads();

    const int f   = t & 127;
    const int ng  = t >> 7;
    const int n0  = ng * 32;
    const int f3  = t & 63;
    const int ng3 = t >> 6;
    const int n03 = ng3 * 16;

    float hreg[32];

#define LAYER128(BB, GG, BE, MM, VV)                                          \
    {                                                                         \
        float sc = GG[f] * rsqrtf(VV[f] + 1e-5f);                             \
        float mu = MM[f], bt = BE[f], bb = BB[f];                             \
        float a[32];                                                          \
        _Pragma("unroll")                                                     \
        for (int i = 0; i < 32; i++) a[i] = 0.f;                              \
        _Pragma("unroll 2")                                                   \
        for (int s = 0; s < 64; s++) {                                        \
            float zv = buf[s * 128 + f];                                      \
            _Pragma("unroll")                                                 \
            for (int qq = 0; qq < 8; qq++) {                                  \
                float4 a4 = *(const float4*)&At[s * 68 + n0 + qq * 4];        \
                a[qq*4+0] += a4.x * zv; a[qq*4+1] += a4.y * zv;               \
                a[qq*4+2] += a4.z * zv; a[qq*4+3] += a4.w * zv;               \
            }                                                                 \
        }                                                                     \
        _Pragma("unroll")                                                     \
        for (int i = 0; i < 32; i++)                                          \
            hreg[i] = fmaxf((a[i] + bb - mu) * sc + bt, 0.f);                 \
    }                                                                         \
    __syncthreads();                                                          \
    _Pragma("unroll")                                                         \
    for (int qq = 0; qq < 8; qq++)                                            \
        *(float4*)&buf[f * 68 + n0 + qq * 4] =                                \
            make_float4(hreg[qq*4], hreg[qq*4+1], hreg[qq*4+2], hreg[qq*4+3]);\
    __syncthreads();

#define GEMM128(WPTR)                                                         \
    {                                                                         \
        float a[32];                                                          \
        _Pragma("unroll")                                                     \
        for (int i = 0; i < 32; i++) a[i] = 0.f;                              \
        _Pragma("unroll 2")                                                   \
        for (int k = 0; k < 128; k++) {                                       \
            float wvv = WPTR[k * 128 + f];                                    \
            _Pragma("unroll")                                                 \
            for (int qq = 0; qq < 8; qq++) {                                  \
                float4 h4 = *(const float4*)&buf[k * 68 + n0 + qq * 4];       \
                a[qq*4+0] += h4.x * wvv; a[qq*4+1] += h4.y * wvv;             \
                a[qq*4+2] += h4.z * wvv; a[qq*4+3] += h4.w * wvv;             \
            }                                                                 \
        }                                                                     \
        __syncthreads();                                                      \
        _Pragma("unroll")                                                     \
        for (int i = 0; i < 32; i++) buf[(n0 + i) * 128 + f] = a[i];          \
        __syncthreads();                                                      \
    }

    LAYER128(b1, g1, be1, m1, v1)      // layer 1 -> hT in buf
    GEMM128(W2)                        // z2 -> zb in buf
    LAYER128(b2, g2, be2, m2, v2)      // layer 2 -> hT in buf

    // GEMM3: z3[n][f3] (OUT3=64)
    {
        float a[16];
        #pragma unroll
        for (int i = 0; i < 16; i++) a[i] = 0.f;
        #pragma unroll 2
        for (int k = 0; k < 128; k++) {
            float wvv = W3[k * 64 + f3];
            #pragma unroll
            for (int qq = 0; qq < 4; qq++) {
                float4 h4 = *(const float4*)&buf[k * 68 + n03 + qq * 4];
                a[qq*4+0] += h4.x * wvv; a[qq*4+1] += h4.y * wvv;
                a[qq*4+2] += h4.z * wvv; a[qq*4+3] += h4.w * wvv;
            }
        }
        __syncthreads();
        #pragma unroll
        for (int i = 0; i < 16; i++) buf[(n03 + i) * 64 + f3] = a[i];
        __syncthreads();
    }

    // layer 3 agg + BN + ReLU + pool partial
    {
        float sc = g3[f3] * rsqrtf(v3[f3] + 1e-5f);
        float mu = m3[f3], bt = be3[f3], bb = b3[f3];
        float a[16];
        #pragma unroll
        for (int i = 0; i < 16; i++) a[i] = 0.f;
        #pragma unroll 2
        for (int s = 0; s < 64; s++) {
            float zv = buf[s * 64 + f3];
            #pragma unroll
            for (int qq = 0; qq < 4; qq++) {
                float4 a4 = *(const float4*)&At[s * 68 + n03 + qq * 4];
                a[qq*4+0] += a4.x * zv; a[qq*4+1] += a4.y * zv;
                a[qq*4+2] += a4.z * zv; a[qq*4+3] += a4.w * zv;
            }
        }
        float psum = 0.f;
        #pragma unroll
        for (int i = 0; i < 16; i++)
            psum += fmaxf((a[i] + bb - mu) * sc + bt, 0.f);
        ps4[ng3 * 64 + f3] = psum;
    }
    __syncthreads();
    if (t < 64) pooled[t] = (ps4[t] + ps4[64 + t] + ps4[128 + t] + ps4[192 + t]) * (1.f / 64.f);
    __syncthreads();
    if (t == 0) {
        float l0 = fcb[0], l1 = fcb[1];
        for (int ff = 0; ff < 64; ff++) { l0 += pooled[ff] * fcw[ff * 2]; l1 += pooled[ff] * fcw[ff * 2 + 1]; }
        float mx  = fmaxf(l0, l1);
        float lse = mx + logf(expf(l0 - mx) + expf(l1 - mx));
        out[g * 2 + 0] = l0 - lse;
        out[g * 2 + 1] = l1 - lse;
    }
#undef LAYER128
#undef GEMM128
}

// ---------------------------------------------------------------- launch
extern "C" void kernel_launch(void* const* d_in, const int* in_sizes, int n_in,
                              void* d_out, int out_size, void* d_ws, size_t ws_size,
                              hipStream_t stream) {
    const float* x   = (const float*)d_in[0];
    const int*   ei  = (const int*)  d_in[1];
    const float* ew  = (const float*)d_in[2];
    const float* cw  = (const float*)d_in[4];
    const float* cb  = (const float*)d_in[5];
    const float* W1  = (const float*)d_in[6];
    const float* b1  = (const float*)d_in[7];
    const float* W2  = (const float*)d_in[8];
    const float* b2  = (const float*)d_in[9];
    const float* W3  = (const float*)d_in[10];
    const float* b3  = (const float*)d_in[11];
    const float* g1  = (const float*)d_in[12];
    const float* be1 = (const float*)d_in[13];
    const float* m1  = (const float*)d_in[14];
    const float* v1  = (const float*)d_in[15];
    const float* g2  = (const float*)d_in[16];
    const float* be2 = (const float*)d_in[17];
    const float* m2  = (const float*)d_in[18];
    const float* v2  = (const float*)d_in[19];
    const float* g3  = (const float*)d_in[20];
    const float* be3 = (const float*)d_in[21];
    const float* m3  = (const float*)d_in[22];
    const float* v3  = (const float*)d_in[23];
    const float* fcw = (const float*)d_in[24];
    const float* fcb = (const float*)d_in[25];
    float* out = (float*)d_out;

    short* wPf = (short*)((char*)d_ws + 16777216);        // 8,192 B
    short* w1f = (short*)((char*)d_ws + 16785408);        // 1,228,800 B

    pack_w  <<<2,   256, 0, stream>>>(cw, wPf);
    pack_w1 <<<300, 256, 0, stream>>>(W1, w1f);
    fused_all<<<NG, 256, 0, stream>>>(x, wPf, cb, w1f, ei, ew,
        b1, g1, be1, m1, v1, W2,
        b2, g2, be2, m2, v2, W3,
        b3, g3, be3, m3, v3, fcw, fcb, out);
}